// Round 11
// baseline (338.961 us; speedup 1.0000x reference)
//
#include <hip/hip_runtime.h>
#include <stdint.h>

// Two-pass select-by-threshold pipeline (R11: no LDS, no barriers; B-fragments
// direct from L2 with REGISTER double-buffering — tile kt+2's loads fly while
// tile kt's MFMAs run; named buffers keep indexing static):
//   k_norm_keys : normalize keys -> bf16 kn + invk; cast q -> qbf; zero cnt
//   k_pass1     : bf16 MFMA sims; per-stream running MAX (1 v_max per result)
//   k_thresh    : T = 8th-largest of PPART*16 stream maxima - margin (T<=v8)
//   k_pass2     : recompute bit-identical sims; collect keys >= T (rare atomics)
//   k_final     : exact fp32 re-dot of <=32 candidates -> top-8, softmax, gather
// ws: [kn N*256B][invk N*4][qbf Q*256B][smax PPART*Q*16*4][thr Q*4][cnt Q*4][cbuf Q*32*4]

typedef unsigned int u32;
typedef unsigned long long u64;
typedef unsigned short u16;
typedef __attribute__((ext_vector_type(4))) float f32x4;
typedef __attribute__((ext_vector_type(2))) float f32x2;
typedef __attribute__((ext_vector_type(8))) short s16x8;  // 8 bf16 in 4 VGPRs

#define D 128
#define QW 64        // queries per wave
#define QB 256       // queries per block (4 waves, independent — no barriers)
#define CMAX 32      // candidate buffer per query
#define MARGIN 0.05f // threshold safety margin (cheap: a few extra candidates)
#define PPART_C 64   // key partitions (compile-time nominal; runtime may shrink)

__device__ __forceinline__ u16 f2bf(float f) {           // RNE float->bf16
    u32 b = __float_as_uint(f);
    b += 0x7FFFu + ((b >> 16) & 1u);
    return (u16)(b >> 16);
}
__device__ __forceinline__ u32 ford(float f) {            // order-preserving f32->u32
    u32 b = __float_as_uint(f);
    return (b & 0x80000000u) ? ~b : (b | 0x80000000u);
}
__device__ __forceinline__ float ford_inv(u32 ob) {
    u32 b = (ob & 0x80000000u) ? (ob ^ 0x80000000u) : ~ob;
    return __uint_as_float(b);
}

// ------- kernel 1: normalize keys -> bf16 + invk; raw-cast q -> qbf ---------
__global__ __launch_bounds__(256) void k_norm_keys(
        const float* __restrict__ keys, const float* __restrict__ q,
        u16* __restrict__ kn, float* __restrict__ invk, u16* __restrict__ qbf,
        u32* __restrict__ cnt, int N, int Q) {
    int row = blockIdx.x * 4 + (threadIdx.x >> 6);
    int lane = threadIdx.x & 63;
    if (row >= N) return;
    if (row < Q) {
        if (lane == 0) cnt[row] = 0u;
        f32x2 qv = *(const f32x2*)(q + (size_t)row * D + lane * 2);
        u32 qp = (u32)f2bf(qv.x) | ((u32)f2bf(qv.y) << 16);   // RAW cast (scale-free)
        *(u32*)(qbf + (size_t)row * D + lane * 2) = qp;
    }
    const float* kr = keys + (size_t)row * D;
    f32x2 v = *(const f32x2*)(kr + lane * 2);
    float ss = v.x * v.x + v.y * v.y;
    #pragma unroll
    for (int o = 1; o < 64; o <<= 1) ss += __shfl_xor(ss, o);
    float inv = 1.0f / fmaxf(sqrtf(ss), 1e-12f);
    if (lane == 0) invk[row] = inv;
    u32 packed = (u32)f2bf(v.x * inv) | ((u32)f2bf(v.y * inv) << 16);
    *(u32*)(kn + (size_t)row * D + lane * 2) = packed;
}

// A fragments straight from qbf (both passes read identical bits).
__device__ __forceinline__ void load_afr_bf(const u16* qbf, int qrow_base,
                                            int lrow, int lhi, s16x8 afr[4]) {
    const u16* qrow = qbf + (size_t)(qrow_base + lrow) * D + lhi * 8;
    #pragma unroll
    for (int s = 0; s < 4; ++s) afr[s] = *(const s16x8*)(qrow + s * 32);
}

// Block id -> (p, qb): group the nqb query-blocks of one key partition on one
// XCD (consecutive bids round-robin XCDs). Bijective when PPART % 8 == 0.
__device__ __forceinline__ void decode_bid(int bid, int nqb, int PPART,
                                           int& p, int& qb) {
    if ((PPART & 7) == 0) {
        int xcd = bid & 7, seq = bid >> 3;
        qb = seq % nqb;
        p  = (seq / nqb) * 8 + xcd;
    } else {
        p = bid / nqb; qb = bid % nqb;
    }
}

// B-fragment loads for one 16-key tile: lane l <- key row (key0 + l&15),
// bytes (l>>4)*16 + s*64.  4 x global_load_dwordx4, fully register-resident.
#define LOADB(bdst, gl, kt)                                                  \
    {                                                                        \
        const char* _a = (gl) + (size_t)(kt) * 4096;                         \
        bdst[0] = *(const s16x8*)(_a);                                       \
        bdst[1] = *(const s16x8*)(_a + 64);                                  \
        bdst[2] = *(const s16x8*)(_a + 128);                                 \
        bdst[3] = *(const s16x8*)(_a + 192);                                 \
    }

// ---------------- kernel 2: pass 1 — per-stream max ------------------------
__global__ __launch_bounds__(256, 2) void k_pass1(
        const u16* __restrict__ kn, const u16* __restrict__ qbf,
        float* __restrict__ smax, int Q, int N, int PPART) {
    const int tid = threadIdx.x;
    const int wave = tid >> 6, lane = tid & 63;
    const int lrow = lane & 15, lhi = lane >> 4;
    const int nqb = Q / QB;
    int p, qb;
    decode_bid(blockIdx.x, nqb, PPART, p, qb);
    const int part = N / PPART;
    const int key0 = p * part;
    const int qbase = qb * QB + wave * QW;

    s16x8 afr[4][4];
    #pragma unroll
    for (int qs = 0; qs < 4; ++qs) load_afr_bf(qbf, qbase + qs * 16, lrow, lhi, afr[qs]);

    float m[4][4];   // [qs][r] stream max, folded over all tiles
    #pragma unroll
    for (int qs = 0; qs < 4; ++qs)
        #pragma unroll
        for (int r = 0; r < 4; ++r) m[qs][r] = -3.0e38f;

    const char* gl = (const char*)kn + ((size_t)(key0 + lrow)) * 256 + lhi * 16;
    const int nkt = part >> 4;           // 16-key tiles (64 for PPART=64)

    s16x8 bA[4], bB[4];                  // named dbuf (static indexing)
    LOADB(bA, gl, 0);
    LOADB(bB, gl, 1);

    for (int kt = 0; kt < nkt; kt += 2) {
        // ---- tile kt from bA ----
        #pragma unroll
        for (int qs = 0; qs < 4; ++qs) {
            f32x4 acc = {0.f, 0.f, 0.f, 0.f};
            #pragma unroll
            for (int s = 0; s < 4; ++s)
                acc = __builtin_amdgcn_mfma_f32_16x16x32_bf16(afr[qs][s], bA[s], acc, 0, 0, 0);
            #pragma unroll
            for (int r = 0; r < 4; ++r) m[qs][r] = fmaxf(m[qs][r], acc[r]);
        }
        {   // refill bA with tile kt+2 (clamped: harmless reload of tile 0)
            const int ka = (kt + 2 < nkt) ? kt + 2 : 0;
            LOADB(bA, gl, ka);
        }
        // ---- tile kt+1 from bB ----
        #pragma unroll
        for (int qs = 0; qs < 4; ++qs) {
            f32x4 acc = {0.f, 0.f, 0.f, 0.f};
            #pragma unroll
            for (int s = 0; s < 4; ++s)
                acc = __builtin_amdgcn_mfma_f32_16x16x32_bf16(afr[qs][s], bB[s], acc, 0, 0, 0);
            #pragma unroll
            for (int r = 0; r < 4; ++r) m[qs][r] = fmaxf(m[qs][r], acc[r]);
        }
        {   // refill bB with tile kt+3
            const int kb2 = (kt + 3 < nkt) ? kt + 3 : 0;
            LOADB(bB, gl, kb2);
        }
    }
    // smax layout [p][q][16]: block writes one contiguous 16KB run
    #pragma unroll
    for (int qs = 0; qs < 4; ++qs)
        #pragma unroll
        for (int r = 0; r < 4; ++r) {
            int qq = qbase + qs * 16 + (lhi << 2) + r;
            smax[((size_t)p * Q + qq) * 16 + lrow] = m[qs][r];
        }
}

// ---------------- kernel 3: per-query threshold -----------------------------
__global__ __launch_bounds__(256) void k_thresh(
        const float* __restrict__ smax, float* __restrict__ thr, int Q, int PP) {
    const int wave = threadIdx.x >> 6, lane = threadIdx.x & 63;
    const int qq = blockIdx.x * 4 + wave;
    const int lrow = lane & 15, lhi = lane >> 4;
    const int nv = PP >> 2;          // regs per lane (p = i*4 + lhi), <= 32
    float v[32];
    #pragma unroll
    for (int i = 0; i < 32; ++i)
        v[i] = (i < nv) ? smax[((size_t)(i * 4 + lhi) * Q + qq) * 16 + lrow]
                        : -3.0e38f;
    float h = -3.0e38f;
    #pragma unroll
    for (int round = 0; round < 8; ++round) {
        h = v[0];
        #pragma unroll
        for (int i = 1; i < 32; ++i) h = fmaxf(h, v[i]);
        #pragma unroll
        for (int o = 1; o < 64; o <<= 1) h = fmaxf(h, __shfl_xor(h, o));
        #pragma unroll
        for (int i = 0; i < 32; ++i) if (v[i] == h) v[i] = -3.0e38f;  // knockout
    }
    if (lane == 0) thr[qq] = h - MARGIN;
}

// ---------------- kernel 4: pass 2 — threshold collect ----------------------
__global__ __launch_bounds__(256, 2) void k_pass2(
        const u16* __restrict__ kn, const u16* __restrict__ qbf,
        const float* __restrict__ thr, u32* __restrict__ cnt,
        u32* __restrict__ cbuf, int Q, int N, int PPART) {
    const int tid = threadIdx.x;
    const int wave = tid >> 6, lane = tid & 63;
    const int lrow = lane & 15, lhi = lane >> 4;
    const int nqb = Q / QB;
    int p, qb;
    decode_bid(blockIdx.x, nqb, PPART, p, qb);
    const int part = N / PPART;
    const int key0 = p * part;
    const int qbase = qb * QB + wave * QW;

    s16x8 afr[4][4];
    #pragma unroll
    for (int qs = 0; qs < 4; ++qs) load_afr_bf(qbf, qbase + qs * 16, lrow, lhi, afr[qs]);

    f32x4 t[4];
    #pragma unroll
    for (int qs = 0; qs < 4; ++qs)
        t[qs] = *(const f32x4*)(thr + qbase + qs * 16 + (lhi << 2));

    const char* gl = (const char*)kn + ((size_t)(key0 + lrow)) * 256 + lhi * 16;
    const int nkt = part >> 4;

    s16x8 bA[4], bB[4];
    LOADB(bA, gl, 0);
    LOADB(bB, gl, 1);

    for (int kt = 0; kt < nkt; kt += 2) {
        // ---- tile kt from bA ----
        {
            const u32 key = (u32)(key0 + (kt << 4) + lrow);
            #pragma unroll
            for (int qs = 0; qs < 4; ++qs) {
                f32x4 acc = {0.f, 0.f, 0.f, 0.f};
                #pragma unroll
                for (int s = 0; s < 4; ++s)
                    acc = __builtin_amdgcn_mfma_f32_16x16x32_bf16(afr[qs][s], bA[s], acc, 0, 0, 0);
                if ((acc[0] >= t[qs][0]) | (acc[1] >= t[qs][1]) |
                    (acc[2] >= t[qs][2]) | (acc[3] >= t[qs][3])) {  // rare
                    #pragma unroll
                    for (int r = 0; r < 4; ++r) {
                        if (acc[r] >= t[qs][r]) {
                            int qq = qbase + qs * 16 + (lhi << 2) + r;
                            u32 pos = atomicAdd(&cnt[qq], 1u);
                            if (pos < CMAX) cbuf[(size_t)qq * CMAX + pos] = key;
                        }
                    }
                }
            }
        }
        {
            const int ka = (kt + 2 < nkt) ? kt + 2 : 0;
            LOADB(bA, gl, ka);
        }
        // ---- tile kt+1 from bB ----
        {
            const u32 key = (u32)(key0 + ((kt + 1) << 4) + lrow);
            #pragma unroll
            for (int qs = 0; qs < 4; ++qs) {
                f32x4 acc = {0.f, 0.f, 0.f, 0.f};
                #pragma unroll
                for (int s = 0; s < 4; ++s)
                    acc = __builtin_amdgcn_mfma_f32_16x16x32_bf16(afr[qs][s], bB[s], acc, 0, 0, 0);
                if ((acc[0] >= t[qs][0]) | (acc[1] >= t[qs][1]) |
                    (acc[2] >= t[qs][2]) | (acc[3] >= t[qs][3])) {
                    #pragma unroll
                    for (int r = 0; r < 4; ++r) {
                        if (acc[r] >= t[qs][r]) {
                            int qq = qbase + qs * 16 + (lhi << 2) + r;
                            u32 pos = atomicAdd(&cnt[qq], 1u);
                            if (pos < CMAX) cbuf[(size_t)qq * CMAX + pos] = key;
                        }
                    }
                }
            }
        }
        {
            const int kb2 = (kt + 3 < nkt) ? kt + 3 : 0;
            LOADB(bB, gl, kb2);
        }
    }
}

// ---------------- kernel 5: exact refine -> top-8 -> output -----------------
__global__ __launch_bounds__(256) void k_final(
        const float* __restrict__ q, const float* __restrict__ keys,
        const float* __restrict__ vals, const float* __restrict__ invk,
        const u32* __restrict__ cnt, const u32* __restrict__ cbuf,
        float* __restrict__ pred, float* __restrict__ conf, int Q) {
    const int w = threadIdx.x >> 6;
    const int qq = blockIdx.x * 4 + w;
    const int lane = threadIdx.x & 63;
    __shared__ float qs[4][D];

    const float* qrow = q + (size_t)qq * D;
    f32x2 qv = *(const f32x2*)(qrow + lane * 2);
    qs[w][lane * 2] = qv.x; qs[w][lane * 2 + 1] = qv.y;
    float ss = qv.x * qv.x + qv.y * qv.y;
    #pragma unroll
    for (int o = 1; o < 64; o <<= 1) ss += __shfl_xor(ss, o);
    const float invq = 1.0f / fmaxf(sqrtf(ss), 1e-12f);
    __syncthreads();

    const u32 n = min(cnt[qq], (u32)CMAX);   // >= 8 by construction
    const int c = lane >> 1;                 // candidate id (2 lanes each)
    const int half = lane & 1;
    const bool valid = (u32)c < n;
    const u32 key = valid ? cbuf[(size_t)qq * CMAX + c] : 0u;

    const float* kr = keys + (size_t)key * D + half * 64;
    const float* qsp = &qs[w][half * 64];
    float dot = 0.f;
    #pragma unroll
    for (int j = 0; j < 64; j += 4) {
        f32x4 kv = *(const f32x4*)(kr + j);
        dot += kv.x * qsp[j] + kv.y * qsp[j + 1] + kv.z * qsp[j + 2] + kv.w * qsp[j + 3];
    }
    dot += __shfl_xor(dot, 1);
    const float ex = dot * invk[key] * invq;
    u64 pk = valid ? (((u64)ford(ex) << 32) | (u32)(~key)) : 0ull;

    float accA = 0.f, accB = 0.f, wsum = 0.f, vsum = 0.f, vmax = 0.f;
    #pragma unroll
    for (int r = 0; r < 8; ++r) {
        u64 h = pk;
        #pragma unroll
        for (int o = 1; o < 64; o <<= 1) {
            u64 tt = __shfl_xor(h, o);
            h = tt > h ? tt : h;
        }
        const bool ok = (h != 0ull);
        const float v = ford_inv((u32)(h >> 32));
        const u32 idx = ok ? ~((u32)h) : 0u;
        if (r == 0) vmax = v;
        const float wgt = ok ? expf(v - vmax) : 0.f;
        wsum += wgt; vsum += ok ? v : 0.f;
        const float* vr = vals + (size_t)idx * D;
        accA += wgt * vr[lane];
        accB += wgt * vr[lane + 64];
        if (pk == h) pk = 0ull;   // pop winner
    }
    const float inv_ws = 1.0f / wsum;
    pred[(size_t)qq * D + lane] = accA * inv_ws;
    pred[(size_t)qq * D + lane + 64] = accB * inv_ws;
    if (lane == 0) conf[qq] = fminf(fmaxf(vsum * 0.125f, 0.f), 1.f);
}

// ---------------------------------------------------------------------------
extern "C" void kernel_launch(void* const* d_in, const int* in_sizes, int n_in,
                              void* d_out, int out_size, void* d_ws, size_t ws_size,
                              hipStream_t stream) {
    const float* q    = (const float*)d_in[0];
    const float* keys = (const float*)d_in[1];
    const float* vals = (const float*)d_in[2];
    const int Q = in_sizes[0] / D;
    const int N = in_sizes[1] / D;

    int PPART = PPART_C;  // 1024 blocks; shrink if ws is tight
    auto need = [&](int P) {
        return (size_t)N * D * 2 + (size_t)N * 4 + (size_t)Q * D * 2 +
               (size_t)Q * P * 16 * 4 + (size_t)Q * 4 * 2 + (size_t)Q * CMAX * 4;
    };
    while (PPART > 2 && need(PPART) > ws_size) PPART >>= 1;

    char* ws = (char*)d_ws;
    size_t off = 0;
    u16*   kn   = (u16*)(ws + off);   off += (size_t)N * D * 2;
    float* invk = (float*)(ws + off); off += (size_t)N * 4;
    u16*   qbf  = (u16*)(ws + off);   off += (size_t)Q * D * 2;
    float* smax = (float*)(ws + off); off += (size_t)Q * PPART * 16 * 4;
    float* thr  = (float*)(ws + off); off += (size_t)Q * 4;
    u32*   cnt  = (u32*)(ws + off);   off += (size_t)Q * 4;
    u32*   cbuf = (u32*)(ws + off);   off += (size_t)Q * CMAX * 4;

    float* pred = (float*)d_out;
    float* conf = pred + (size_t)Q * D;

    k_norm_keys<<<(N + 3) / 4, 256, 0, stream>>>(keys, q, kn, invk, qbf, cnt, N, Q);
    k_pass1<<<(Q / QB) * PPART, 256, 0, stream>>>(kn, qbf, smax, Q, N, PPART);
    k_thresh<<<Q / 4, 256, 0, stream>>>(smax, thr, Q, PPART);
    k_pass2<<<(Q / QB) * PPART, 256, 0, stream>>>(kn, qbf, thr, cnt, cbuf, Q, N, PPART);
    k_final<<<Q / 4, 256, 0, stream>>>(q, keys, vals, invk, cnt, cbuf, pred, conf, Q);
}

// Round 12
// 124.670 us; speedup vs baseline: 2.7189x; 2.7189x over previous
//
#include <hip/hip_runtime.h>
#include <stdint.h>

// SINGLE-heavy-pass select-by-threshold pipeline (R12):
//   k_norm_keys : normalize keys -> bf16 kn + invk; cast q -> qbf; zero cnt
//   k_pass1     : bf16 MFMA sims with 8-bit TILE TAG injected into the low
//                 mantissa bits of each result (error <= 3e-5, << MARGIN).
//                 Per stream (p, j): branchless top-2 via v_max + v_med3 —
//                 the value itself carries the key. No second scan needed.
//   k_select    : per query: T = 8th-largest stream-hi - margin; append keys
//                 of all hi/sec entries >= T (decoded from tag) to cbuf.
//                 Guarantee: top-8 exact keys are each argmax or 2nd of their
//                 stream (3-in-stream prob ~2e-4 total); hi/sec >= T covered.
//   k_final     : exact fp32 re-dot of <=64 candidates -> top-8, softmax,
//                 gather vals, conf.
// ws: [kn N*256B][invk N*4][qbf Q*256B][shi PPART*Q*16*4][ssec same][cnt Q*4]
//     [cbuf Q*64*4]

typedef unsigned int u32;
typedef unsigned long long u64;
typedef unsigned short u16;
typedef __attribute__((ext_vector_type(4))) float f32x4;
typedef __attribute__((ext_vector_type(2))) float f32x2;
typedef __attribute__((ext_vector_type(4))) int i32x4;
typedef __attribute__((ext_vector_type(8))) short s16x8;  // 8 bf16 in 4 VGPRs

#define D 128
#define KTILE 64     // keys per LDS tile (16 KB, single buffer) — R7-proven
#define QW 64        // queries per wave
#define QB 256       // queries per block (4 waves)
#define CMAX 64      // candidate buffer per query
#define MARGIN 0.05f // threshold safety margin (covers bf16 + tag perturbation)
#define TBYTES (KTILE * 256)

__device__ __forceinline__ u16 f2bf(float f) {           // RNE float->bf16
    u32 b = __float_as_uint(f);
    b += 0x7FFFu + ((b >> 16) & 1u);
    return (u16)(b >> 16);
}
__device__ __forceinline__ u32 ford(float f) {            // order-preserving f32->u32
    u32 b = __float_as_uint(f);
    return (b & 0x80000000u) ? ~b : (b | 0x80000000u);
}
__device__ __forceinline__ float ford_inv(u32 ob) {
    u32 b = (ob & 0x80000000u) ? (ob ^ 0x80000000u) : ~ob;
    return __uint_as_float(b);
}

// ------- kernel 1: normalize keys -> bf16 + invk; raw-cast q -> qbf ---------
__global__ __launch_bounds__(256) void k_norm_keys(
        const float* __restrict__ keys, const float* __restrict__ q,
        u16* __restrict__ kn, float* __restrict__ invk, u16* __restrict__ qbf,
        u32* __restrict__ cnt, int N, int Q) {
    int row = blockIdx.x * 4 + (threadIdx.x >> 6);
    int lane = threadIdx.x & 63;
    if (row >= N) return;
    if (row < Q) {
        if (lane == 0) cnt[row] = 0u;
        f32x2 qv = *(const f32x2*)(q + (size_t)row * D + lane * 2);
        u32 qp = (u32)f2bf(qv.x) | ((u32)f2bf(qv.y) << 16);   // RAW cast (scale-free)
        *(u32*)(qbf + (size_t)row * D + lane * 2) = qp;
    }
    const float* kr = keys + (size_t)row * D;
    f32x2 v = *(const f32x2*)(kr + lane * 2);
    float ss = v.x * v.x + v.y * v.y;
    #pragma unroll
    for (int o = 1; o < 64; o <<= 1) ss += __shfl_xor(ss, o);
    float inv = 1.0f / fmaxf(sqrtf(ss), 1e-12f);
    if (lane == 0) invk[row] = inv;
    u32 packed = (u32)f2bf(v.x * inv) | ((u32)f2bf(v.y * inv) << 16);
    *(u32*)(kn + (size_t)row * D + lane * 2) = packed;
}

// A fragments straight from qbf.
__device__ __forceinline__ void load_afr_bf(const u16* qbf, int qrow_base,
                                            int lrow, int lhi, s16x8 afr[4]) {
    const u16* qrow = qbf + (size_t)(qrow_base + lrow) * D + lhi * 8;
    #pragma unroll
    for (int s = 0; s < 4; ++s) afr[s] = *(const s16x8*)(qrow + s * 32);
}

// Block id -> (p, qb): group the nqb query-blocks of one key partition on one
// XCD (consecutive bids round-robin XCDs). Bijective when PPART % 8 == 0.
__device__ __forceinline__ void decode_bid(int bid, int nqb, int PPART,
                                           int& p, int& qb) {
    if ((PPART & 7) == 0) {
        int xcd = bid & 7, seq = bid >> 3;
        qb = seq % nqb;
        p  = (seq / nqb) * 8 + xcd;
    } else {
        p = bid / nqb; qb = bid % nqb;
    }
}

// LDS swizzle contract (R7-proven): slot (row r, 16B-granule g) holds global
// granule g ^ (r&15). Writes: reg-staged ds_write_b128 at granule g^(r&15).
// Reads: slot granule (4s+lhi)^lrow at row kt*16+lrow -> global chunk 4s+lhi.

// ---------------- kernel 2: the ONLY heavy pass — tagged top-2 per stream ---
__global__ __launch_bounds__(256, 2) void k_pass1(
        const u16* __restrict__ kn, const u16* __restrict__ qbf,
        float* __restrict__ shi, float* __restrict__ ssec,
        int Q, int N, int PPART) {
    __shared__ __align__(16) char lds[TBYTES];   // 16 KB single buffer
    const int tid = threadIdx.x;
    const int wave = tid >> 6, lane = tid & 63;
    const int lrow = lane & 15, lhi = lane >> 4;
    const int nqb = Q / QB;
    int p, qb;
    decode_bid(blockIdx.x, nqb, PPART, p, qb);
    const int part = N / PPART;
    const int key0 = p * part;
    const int qbase = qb * QB + wave * QW;

    s16x8 afr[4][4];
    #pragma unroll
    for (int qs = 0; qs < 4; ++qs) load_afr_bf(qbf, qbase + qs * 16, lrow, lhi, afr[qs]);

    float hi[4][4], sec[4][4];   // per-stream top-2 tagged values
    #pragma unroll
    for (int qs = 0; qs < 4; ++qs)
        #pragma unroll
        for (int r = 0; r < 4; ++r) { hi[qs][r] = -3.0e38f; sec[qs][r] = -3.0e38f; }

    int roff[4];
    #pragma unroll
    for (int s = 0; s < 4; ++s)
        roff[s] = lrow * 256 + ((((s << 2) + lhi) ^ lrow) << 4);

    // staging: thread t -> row t>>2, granules (t&3)*4 + 0..3 (64B contiguous)
    const int srow = tid >> 2;
    const int sg0  = (tid & 3) << 2;
    const int sx   = srow & 15;
    int woff[4];
    #pragma unroll
    for (int i = 0; i < 4; ++i) woff[i] = srow * 256 + (((sg0 + i) ^ sx) << 4);
    const char* gsrc = (const char*)kn + ((size_t)(key0 + srow)) * 256 + sg0 * 16;

    const int iters = part / KTILE;
    i32x4 v[4];
    #pragma unroll
    for (int i = 0; i < 4; ++i) v[i] = *(const i32x4*)(gsrc + i * 16);

    for (int kb = 0; kb < iters; ++kb) {
        __syncthreads();   // (A) prev-tile readers done
        #pragma unroll
        for (int i = 0; i < 4; ++i) *(i32x4*)(lds + woff[i]) = v[i];
        __syncthreads();   // (B) writes visible
        if (kb + 1 < iters) {   // issue AFTER barrier; drained at next (A)
            const char* gn = gsrc + (size_t)(kb + 1) * TBYTES;
            #pragma unroll
            for (int i = 0; i < 4; ++i) v[i] = *(const i32x4*)(gn + i * 16);
        }
        __builtin_amdgcn_s_setprio(1);
        #pragma unroll
        for (int kt = 0; kt < 4; ++kt) {
            const u32 tag = (u32)((kb << 2) + kt);   // tile-of-16 index, < 256
            s16x8 bfr[4];
            #pragma unroll
            for (int s = 0; s < 4; ++s)
                bfr[s] = *(const s16x8*)(lds + roff[s] + kt * 4096);
            #pragma unroll
            for (int qs = 0; qs < 4; ++qs) {
                f32x4 acc = {0.f, 0.f, 0.f, 0.f};
                #pragma unroll
                for (int s = 0; s < 4; ++s)
                    acc = __builtin_amdgcn_mfma_f32_16x16x32_bf16(afr[qs][s], bfr[s], acc, 0, 0, 0);
                #pragma unroll
                for (int r = 0; r < 4; ++r) {
                    // inject tag into low 8 mantissa bits (err <= 3e-5)
                    float tf = __uint_as_float(
                        (__float_as_uint(acc[r]) & 0xFFFFFF00u) | tag);
                    float h0 = hi[qs][r];
                    sec[qs][r] = __builtin_amdgcn_fmed3f(tf, sec[qs][r], h0);
                    hi[qs][r]  = fmaxf(h0, tf);
                }
            }
        }
        __builtin_amdgcn_s_setprio(0);
    }
    // layout [p][q][16]: block writes contiguous runs
    #pragma unroll
    for (int qs = 0; qs < 4; ++qs)
        #pragma unroll
        for (int r = 0; r < 4; ++r) {
            int qq = qbase + qs * 16 + (lhi << 2) + r;
            shi [((size_t)p * Q + qq) * 16 + lrow] = hi[qs][r];
            ssec[((size_t)p * Q + qq) * 16 + lrow] = sec[qs][r];
        }
}

// -------- kernel 3: merged threshold + candidate collection -----------------
__global__ __launch_bounds__(256) void k_select(
        const float* __restrict__ shi, const float* __restrict__ ssec,
        u32* __restrict__ cnt, u32* __restrict__ cbuf, int Q, int N, int PPART) {
    const int wave = threadIdx.x >> 6, lane = threadIdx.x & 63;
    const int qq = blockIdx.x * 4 + wave;
    const int nv = PPART >> 2;        // streams per lane (<=16 for PPART<=64)
    float v[16], w[16], sc[16];
    #pragma unroll
    for (int i = 0; i < 16; ++i) {
        if (i < nv) {
            size_t base = ((size_t)(i * 4 + (lane >> 4)) * Q + qq) * 16 + (lane & 15);
            w[i] = v[i] = shi[base];
            sc[i] = ssec[base];
        } else { w[i] = v[i] = sc[i] = -3.0e38f; }
    }
    // T = 8th-largest stream-hi (knockout; value-dups collapse -> smaller T = safe)
    float h = -3.0e38f;
    #pragma unroll
    for (int round = 0; round < 8; ++round) {
        h = v[0];
        #pragma unroll
        for (int i = 1; i < 16; ++i) h = fmaxf(h, v[i]);
        #pragma unroll
        for (int o = 1; o < 64; o <<= 1) h = fmaxf(h, __shfl_xor(h, o));
        #pragma unroll
        for (int i = 0; i < 16; ++i) if (v[i] == h) v[i] = -3.0e38f;
    }
    const float T = h - MARGIN;
    const int part = N / PPART;
    #pragma unroll
    for (int i = 0; i < 16; ++i) {
        if (i >= nv) break;
        const int sidx = i * 64 + lane;        // stream = (p = sidx>>4, j = sidx&15)
        const int p = sidx >> 4, j = sidx & 15;
        if (w[i] >= T) {
            u32 key = (u32)(p * part + (int)((__float_as_uint(w[i]) & 255u) << 4) + j);
            u32 pos = atomicAdd(&cnt[qq], 1u);
            if (pos < CMAX) cbuf[(size_t)qq * CMAX + pos] = key;
        }
        if (sc[i] >= T) {
            u32 key = (u32)(p * part + (int)((__float_as_uint(sc[i]) & 255u) << 4) + j);
            u32 pos = atomicAdd(&cnt[qq], 1u);
            if (pos < CMAX) cbuf[(size_t)qq * CMAX + pos] = key;
        }
    }
}

// ---------------- kernel 4: exact refine -> top-8 -> output -----------------
__global__ __launch_bounds__(256) void k_final(
        const float* __restrict__ q, const float* __restrict__ keys,
        const float* __restrict__ vals, const float* __restrict__ invk,
        const u32* __restrict__ cnt, const u32* __restrict__ cbuf,
        float* __restrict__ pred, float* __restrict__ conf, int Q) {
    const int w = threadIdx.x >> 6;
    const int qq = blockIdx.x * 4 + w;
    const int lane = threadIdx.x & 63;
    __shared__ float qs[4][D];

    const float* qrow = q + (size_t)qq * D;
    f32x2 qv = *(const f32x2*)(qrow + lane * 2);
    qs[w][lane * 2] = qv.x; qs[w][lane * 2 + 1] = qv.y;
    float ss = qv.x * qv.x + qv.y * qv.y;
    #pragma unroll
    for (int o = 1; o < 64; o <<= 1) ss += __shfl_xor(ss, o);
    const float invq = 1.0f / fmaxf(sqrtf(ss), 1e-12f);
    __syncthreads();

    const u32 n = min(cnt[qq], (u32)CMAX);   // >= 8 by construction
    const int c0 = lane >> 1;                // candidates c0 and c0+32
    const int half = lane & 1;
    const bool valid0 = (u32)c0 < n;
    const bool valid1 = (u32)(c0 + 32) < n;
    const u32 key0 = valid0 ? cbuf[(size_t)qq * CMAX + c0] : 0u;
    const u32 key1 = valid1 ? cbuf[(size_t)qq * CMAX + c0 + 32] : 0u;

    const float* qsp = &qs[w][half * 64];
    float dot0 = 0.f, dot1 = 0.f;
    {
        const float* kr0 = keys + (size_t)key0 * D + half * 64;
        const float* kr1 = keys + (size_t)key1 * D + half * 64;
        #pragma unroll
        for (int j = 0; j < 64; j += 4) {
            f32x4 a = *(const f32x4*)(kr0 + j);
            f32x4 b = *(const f32x4*)(kr1 + j);
            dot0 += a.x * qsp[j] + a.y * qsp[j + 1] + a.z * qsp[j + 2] + a.w * qsp[j + 3];
            dot1 += b.x * qsp[j] + b.y * qsp[j + 1] + b.z * qsp[j + 2] + b.w * qsp[j + 3];
        }
    }
    dot0 += __shfl_xor(dot0, 1);
    dot1 += __shfl_xor(dot1, 1);
    const float ex0 = dot0 * invk[key0] * invq;
    const float ex1 = dot1 * invk[key1] * invq;
    // pack with ~key so ties prefer the smaller index (jax top_k order)
    u64 pkA = valid0 ? (((u64)ford(ex0) << 32) | (u32)(~key0)) : 0ull;
    u64 pkB = valid1 ? (((u64)ford(ex1) << 32) | (u32)(~key1)) : 0ull;

    float accA = 0.f, accB = 0.f, wsum = 0.f, vsum = 0.f, vmax = 0.f;
    #pragma unroll
    for (int r = 0; r < 8; ++r) {
        u64 mx = pkA > pkB ? pkA : pkB;
        u64 hh = mx;
        #pragma unroll
        for (int o = 1; o < 64; o <<= 1) {
            u64 tt = __shfl_xor(hh, o);
            hh = tt > hh ? tt : hh;
        }
        const bool ok = (hh != 0ull);
        const float vv = ford_inv((u32)(hh >> 32));
        const u32 idx = ok ? ~((u32)hh) : 0u;
        if (r == 0) vmax = vv;
        const float wgt = ok ? expf(vv - vmax) : 0.f;
        wsum += wgt; vsum += ok ? vv : 0.f;
        const float* vr = vals + (size_t)idx * D;
        accA += wgt * vr[lane];
        accB += wgt * vr[lane + 64];
        if (pkA == hh) pkA = 0ull;   // pop winner (keys unique -> pk unique)
        if (pkB == hh) pkB = 0ull;
    }
    const float inv_ws = 1.0f / wsum;
    pred[(size_t)qq * D + lane] = accA * inv_ws;
    pred[(size_t)qq * D + lane + 64] = accB * inv_ws;
    if (lane == 0) conf[qq] = fminf(fmaxf(vsum * 0.125f, 0.f), 1.f);
}

// ---------------------------------------------------------------------------
extern "C" void kernel_launch(void* const* d_in, const int* in_sizes, int n_in,
                              void* d_out, int out_size, void* d_ws, size_t ws_size,
                              hipStream_t stream) {
    const float* q    = (const float*)d_in[0];
    const float* keys = (const float*)d_in[1];
    const float* vals = (const float*)d_in[2];
    const int Q = in_sizes[0] / D;
    const int N = in_sizes[1] / D;

    int PPART = 64;  // 1024 blocks (R7-proven); shrink if ws is tight
    auto need = [&](int P) {
        return (size_t)N * D * 2 + (size_t)N * 4 + (size_t)Q * D * 2 +
               2 * ((size_t)Q * P * 16 * 4) + (size_t)Q * 4 +
               (size_t)Q * CMAX * 4;
    };
    while (PPART > 2 && need(PPART) > ws_size) PPART >>= 1;

    char* ws = (char*)d_ws;
    size_t off = 0;
    u16*   kn   = (u16*)(ws + off);   off += (size_t)N * D * 2;
    float* invk = (float*)(ws + off); off += (size_t)N * 4;
    u16*   qbf  = (u16*)(ws + off);   off += (size_t)Q * D * 2;
    float* shi  = (float*)(ws + off); off += (size_t)Q * PPART * 16 * 4;
    float* ssec = (float*)(ws + off); off += (size_t)Q * PPART * 16 * 4;
    u32*   cnt  = (u32*)(ws + off);   off += (size_t)Q * 4;
    u32*   cbuf = (u32*)(ws + off);   off += (size_t)Q * CMAX * 4;

    float* pred = (float*)d_out;
    float* conf = pred + (size_t)Q * D;

    k_norm_keys<<<(N + 3) / 4, 256, 0, stream>>>(keys, q, kn, invk, qbf, cnt, N, Q);
    k_pass1<<<(Q / QB) * PPART, 256, 0, stream>>>(kn, qbf, shi, ssec, Q, N, PPART);
    k_select<<<Q / 4, 256, 0, stream>>>(shi, ssec, cnt, cbuf, Q, N, PPART);
    k_final<<<Q / 4, 256, 0, stream>>>(q, keys, vals, invk, cnt, cbuf, pred, conf, Q);
}

// Round 14
// 124.474 us; speedup vs baseline: 2.7232x; 1.0016x over previous
//
#include <hip/hip_runtime.h>
#include <stdint.h>

// SINGLE-heavy-pass select-by-threshold pipeline (R14 = R12 + SAFE VALU
// micro-opts only: hoisted zero-acc seed, pointer-bump staging. The R13
// inline-asm v_and_or_b32 crashed at runtime — reverted to plain C, which
// the AMDGPU backend fuses to v_and_or_b32 anyway):
//   k_norm_keys : normalize keys -> bf16 kn + invk; cast q -> qbf; zero cnt
//   k_pass1     : bf16 MFMA sims with 8-bit TILE TAG injected into the low
//                 mantissa bits (err <= 3e-5 << MARGIN). Per stream (p,j):
//                 branchless top-2 via v_med3 + v_max; value carries the key.
//   k_select    : per query: T = 8th-largest stream-hi - margin; append keys
//                 of all hi/sec entries >= T (decoded from tag).
//   k_final     : exact fp32 re-dot of <=64 candidates -> top-8, softmax,
//                 gather vals, conf.
// ws: [kn N*256B][invk N*4][qbf Q*256B][shi PPART*Q*16*4][ssec same][cnt Q*4]
//     [cbuf Q*64*4]

typedef unsigned int u32;
typedef unsigned long long u64;
typedef unsigned short u16;
typedef __attribute__((ext_vector_type(4))) float f32x4;
typedef __attribute__((ext_vector_type(2))) float f32x2;
typedef __attribute__((ext_vector_type(4))) int i32x4;
typedef __attribute__((ext_vector_type(8))) short s16x8;  // 8 bf16 in 4 VGPRs

#define D 128
#define KTILE 64     // keys per LDS tile (16 KB, single buffer) — R7-proven
#define QW 64        // queries per wave
#define QB 256       // queries per block (4 waves)
#define CMAX 64      // candidate buffer per query
#define MARGIN 0.05f // threshold safety margin (covers bf16 + tag perturbation)
#define TBYTES (KTILE * 256)

__device__ __forceinline__ u16 f2bf(float f) {           // RNE float->bf16
    u32 b = __float_as_uint(f);
    b += 0x7FFFu + ((b >> 16) & 1u);
    return (u16)(b >> 16);
}
__device__ __forceinline__ u32 ford(float f) {            // order-preserving f32->u32
    u32 b = __float_as_uint(f);
    return (b & 0x80000000u) ? ~b : (b | 0x80000000u);
}
__device__ __forceinline__ float ford_inv(u32 ob) {
    u32 b = (ob & 0x80000000u) ? (ob ^ 0x80000000u) : ~ob;
    return __uint_as_float(b);
}

// ------- kernel 1: normalize keys -> bf16 + invk; raw-cast q -> qbf ---------
__global__ __launch_bounds__(256) void k_norm_keys(
        const float* __restrict__ keys, const float* __restrict__ q,
        u16* __restrict__ kn, float* __restrict__ invk, u16* __restrict__ qbf,
        u32* __restrict__ cnt, int N, int Q) {
    int row = blockIdx.x * 4 + (threadIdx.x >> 6);
    int lane = threadIdx.x & 63;
    if (row >= N) return;
    if (row < Q) {
        if (lane == 0) cnt[row] = 0u;
        f32x2 qv = *(const f32x2*)(q + (size_t)row * D + lane * 2);
        u32 qp = (u32)f2bf(qv.x) | ((u32)f2bf(qv.y) << 16);   // RAW cast (scale-free)
        *(u32*)(qbf + (size_t)row * D + lane * 2) = qp;
    }
    const float* kr = keys + (size_t)row * D;
    f32x2 v = *(const f32x2*)(kr + lane * 2);
    float ss = v.x * v.x + v.y * v.y;
    #pragma unroll
    for (int o = 1; o < 64; o <<= 1) ss += __shfl_xor(ss, o);
    float inv = 1.0f / fmaxf(sqrtf(ss), 1e-12f);
    if (lane == 0) invk[row] = inv;
    u32 packed = (u32)f2bf(v.x * inv) | ((u32)f2bf(v.y * inv) << 16);
    *(u32*)(kn + (size_t)row * D + lane * 2) = packed;
}

// A fragments straight from qbf.
__device__ __forceinline__ void load_afr_bf(const u16* qbf, int qrow_base,
                                            int lrow, int lhi, s16x8 afr[4]) {
    const u16* qrow = qbf + (size_t)(qrow_base + lrow) * D + lhi * 8;
    #pragma unroll
    for (int s = 0; s < 4; ++s) afr[s] = *(const s16x8*)(qrow + s * 32);
}

// Block id -> (p, qb): group the nqb query-blocks of one key partition on one
// XCD (consecutive bids round-robin XCDs). Bijective when PPART % 8 == 0.
__device__ __forceinline__ void decode_bid(int bid, int nqb, int PPART,
                                           int& p, int& qb) {
    if ((PPART & 7) == 0) {
        int xcd = bid & 7, seq = bid >> 3;
        qb = seq % nqb;
        p  = (seq / nqb) * 8 + xcd;
    } else {
        p = bid / nqb; qb = bid % nqb;
    }
}

// LDS swizzle contract (R7-proven): slot (row r, 16B-granule g) holds global
// granule g ^ (r&15). Writes: reg-staged ds_write_b128 at granule g^(r&15).
// Reads: slot granule (4s+lhi)^lrow at row kt*16+lrow -> global chunk 4s+lhi.

// ---------------- kernel 2: the ONLY heavy pass — tagged top-2 per stream ---
__global__ __launch_bounds__(256, 2) void k_pass1(
        const u16* __restrict__ kn, const u16* __restrict__ qbf,
        float* __restrict__ shi, float* __restrict__ ssec,
        int Q, int N, int PPART) {
    __shared__ __align__(16) char lds[TBYTES];   // 16 KB single buffer
    const int tid = threadIdx.x;
    const int wave = tid >> 6, lane = tid & 63;
    const int lrow = lane & 15, lhi = lane >> 4;
    const int nqb = Q / QB;
    int p, qb;
    decode_bid(blockIdx.x, nqb, PPART, p, qb);
    const int part = N / PPART;
    const int key0 = p * part;
    const int qbase = qb * QB + wave * QW;

    s16x8 afr[4][4];
    #pragma unroll
    for (int qs = 0; qs < 4; ++qs) load_afr_bf(qbf, qbase + qs * 16, lrow, lhi, afr[qs]);

    float hi[4][4], sec[4][4];   // per-stream top-2 tagged values
    #pragma unroll
    for (int qs = 0; qs < 4; ++qs)
        #pragma unroll
        for (int r = 0; r < 4; ++r) { hi[qs][r] = -3.0e38f; sec[qs][r] = -3.0e38f; }

    int roff[4];
    #pragma unroll
    for (int s = 0; s < 4; ++s)
        roff[s] = lrow * 256 + ((((s << 2) + lhi) ^ lrow) << 4);

    // staging: thread t -> row t>>2, granules (t&3)*4 + 0..3 (64B contiguous)
    const int srow = tid >> 2;
    const int sg0  = (tid & 3) << 2;
    const int sx   = srow & 15;
    int woff[4];
    #pragma unroll
    for (int i = 0; i < 4; ++i) woff[i] = srow * 256 + (((sg0 + i) ^ sx) << 4);
    const char* gsrc = (const char*)kn + ((size_t)(key0 + srow)) * 256 + sg0 * 16;

    const int iters = part / KTILE;
    i32x4 v[4];
    #pragma unroll
    for (int i = 0; i < 4; ++i) v[i] = *(const i32x4*)(gsrc + i * 16);
    const char* gnext = gsrc + TBYTES;

    const f32x4 kZero = {0.f, 0.f, 0.f, 0.f};   // hoisted acc seed (no per-kt movs)

    for (int kb = 0; kb < iters; ++kb) {
        __syncthreads();   // (A) prev-tile readers done
        #pragma unroll
        for (int i = 0; i < 4; ++i) *(i32x4*)(lds + woff[i]) = v[i];
        __syncthreads();   // (B) writes visible
        if (kb + 1 < iters) {   // issue AFTER barrier; drained at next (A)
            #pragma unroll
            for (int i = 0; i < 4; ++i) v[i] = *(const i32x4*)(gnext + i * 16);
            gnext += TBYTES;
        }
        __builtin_amdgcn_s_setprio(1);
        #pragma unroll
        for (int kt = 0; kt < 4; ++kt) {
            const u32 tag = (u32)((kb << 2) + kt);   // tile-of-16 index, < 256
            s16x8 bfr[4];
            #pragma unroll
            for (int s = 0; s < 4; ++s)
                bfr[s] = *(const s16x8*)(lds + roff[s] + kt * 4096);
            #pragma unroll
            for (int qs = 0; qs < 4; ++qs) {
                f32x4 acc = __builtin_amdgcn_mfma_f32_16x16x32_bf16(
                                afr[qs][0], bfr[0], kZero, 0, 0, 0);
                #pragma unroll
                for (int s = 1; s < 4; ++s)
                    acc = __builtin_amdgcn_mfma_f32_16x16x32_bf16(afr[qs][s], bfr[s], acc, 0, 0, 0);
                #pragma unroll
                for (int r = 0; r < 4; ++r) {
                    // (acc & 0xFFFFFF00) | tag — backend fuses to v_and_or_b32
                    float tf = __uint_as_float(
                        (__float_as_uint(acc[r]) & 0xFFFFFF00u) | tag);
                    float h0 = hi[qs][r];
                    sec[qs][r] = __builtin_amdgcn_fmed3f(tf, sec[qs][r], h0);
                    hi[qs][r]  = fmaxf(h0, tf);
                }
            }
        }
        __builtin_amdgcn_s_setprio(0);
    }
    // layout [p][q][16]: block writes contiguous runs
    #pragma unroll
    for (int qs = 0; qs < 4; ++qs)
        #pragma unroll
        for (int r = 0; r < 4; ++r) {
            int qq = qbase + qs * 16 + (lhi << 2) + r;
            shi [((size_t)p * Q + qq) * 16 + lrow] = hi[qs][r];
            ssec[((size_t)p * Q + qq) * 16 + lrow] = sec[qs][r];
        }
}

// -------- kernel 3: merged threshold + candidate collection -----------------
__global__ __launch_bounds__(256) void k_select(
        const float* __restrict__ shi, const float* __restrict__ ssec,
        u32* __restrict__ cnt, u32* __restrict__ cbuf, int Q, int N, int PPART) {
    const int wave = threadIdx.x >> 6, lane = threadIdx.x & 63;
    const int qq = blockIdx.x * 4 + wave;
    const int nv = PPART >> 2;        // streams per lane (<=16 for PPART<=64)
    float v[16], w[16], sc[16];
    #pragma unroll
    for (int i = 0; i < 16; ++i) {
        if (i < nv) {
            size_t base = ((size_t)(i * 4 + (lane >> 4)) * Q + qq) * 16 + (lane & 15);
            w[i] = v[i] = shi[base];
            sc[i] = ssec[base];
        } else { w[i] = v[i] = sc[i] = -3.0e38f; }
    }
    // T = 8th-largest stream-hi (knockout; value-dups collapse -> smaller T = safe)
    float h = -3.0e38f;
    #pragma unroll
    for (int round = 0; round < 8; ++round) {
        h = v[0];
        #pragma unroll
        for (int i = 1; i < 16; ++i) h = fmaxf(h, v[i]);
        #pragma unroll
        for (int o = 1; o < 64; o <<= 1) h = fmaxf(h, __shfl_xor(h, o));
        #pragma unroll
        for (int i = 0; i < 16; ++i) if (v[i] == h) v[i] = -3.0e38f;
    }
    const float T = h - MARGIN;
    const int part = N / PPART;
    #pragma unroll
    for (int i = 0; i < 16; ++i) {
        if (i >= nv) break;
        const int sidx = i * 64 + lane;        // stream = (p = sidx>>4, j = sidx&15)
        const int p = sidx >> 4, j = sidx & 15;
        if (w[i] >= T) {
            u32 key = (u32)(p * part + (int)((__float_as_uint(w[i]) & 255u) << 4) + j);
            u32 pos = atomicAdd(&cnt[qq], 1u);
            if (pos < CMAX) cbuf[(size_t)qq * CMAX + pos] = key;
        }
        if (sc[i] >= T) {
            u32 key = (u32)(p * part + (int)((__float_as_uint(sc[i]) & 255u) << 4) + j);
            u32 pos = atomicAdd(&cnt[qq], 1u);
            if (pos < CMAX) cbuf[(size_t)qq * CMAX + pos] = key;
        }
    }
}

// ---------------- kernel 4: exact refine -> top-8 -> output -----------------
__global__ __launch_bounds__(256) void k_final(
        const float* __restrict__ q, const float* __restrict__ keys,
        const float* __restrict__ vals, const float* __restrict__ invk,
        const u32* __restrict__ cnt, const u32* __restrict__ cbuf,
        float* __restrict__ pred, float* __restrict__ conf, int Q) {
    const int w = threadIdx.x >> 6;
    const int qq = blockIdx.x * 4 + w;
    const int lane = threadIdx.x & 63;
    __shared__ float qs[4][D];

    const float* qrow = q + (size_t)qq * D;
    f32x2 qv = *(const f32x2*)(qrow + lane * 2);
    qs[w][lane * 2] = qv.x; qs[w][lane * 2 + 1] = qv.y;
    float ss = qv.x * qv.x + qv.y * qv.y;
    #pragma unroll
    for (int o = 1; o < 64; o <<= 1) ss += __shfl_xor(ss, o);
    const float invq = 1.0f / fmaxf(sqrtf(ss), 1e-12f);
    __syncthreads();

    const u32 n = min(cnt[qq], (u32)CMAX);   // >= 8 by construction
    const int c0 = lane >> 1;                // candidates c0 and c0+32
    const int half = lane & 1;
    const bool valid0 = (u32)c0 < n;
    const bool valid1 = (u32)(c0 + 32) < n;
    const u32 key0 = valid0 ? cbuf[(size_t)qq * CMAX + c0] : 0u;
    const u32 key1 = valid1 ? cbuf[(size_t)qq * CMAX + c0 + 32] : 0u;

    const float* qsp = &qs[w][half * 64];
    float dot0 = 0.f, dot1 = 0.f;
    {
        const float* kr0 = keys + (size_t)key0 * D + half * 64;
        const float* kr1 = keys + (size_t)key1 * D + half * 64;
        #pragma unroll
        for (int j = 0; j < 64; j += 4) {
            f32x4 a = *(const f32x4*)(kr0 + j);
            f32x4 b = *(const f32x4*)(kr1 + j);
            dot0 += a.x * qsp[j] + a.y * qsp[j + 1] + a.z * qsp[j + 2] + a.w * qsp[j + 3];
            dot1 += b.x * qsp[j] + b.y * qsp[j + 1] + b.z * qsp[j + 2] + b.w * qsp[j + 3];
        }
    }
    dot0 += __shfl_xor(dot0, 1);
    dot1 += __shfl_xor(dot1, 1);
    const float ex0 = dot0 * invk[key0] * invq;
    const float ex1 = dot1 * invk[key1] * invq;
    // pack with ~key so ties prefer the smaller index (jax top_k order)
    u64 pkA = valid0 ? (((u64)ford(ex0) << 32) | (u32)(~key0)) : 0ull;
    u64 pkB = valid1 ? (((u64)ford(ex1) << 32) | (u32)(~key1)) : 0ull;

    float accA = 0.f, accB = 0.f, wsum = 0.f, vsum = 0.f, vmax = 0.f;
    #pragma unroll
    for (int r = 0; r < 8; ++r) {
        u64 mx = pkA > pkB ? pkA : pkB;
        u64 hh = mx;
        #pragma unroll
        for (int o = 1; o < 64; o <<= 1) {
            u64 tt = __shfl_xor(hh, o);
            hh = tt > hh ? tt : hh;
        }
        const bool ok = (hh != 0ull);
        const float vv = ford_inv((u32)(hh >> 32));
        const u32 idx = ok ? ~((u32)hh) : 0u;
        if (r == 0) vmax = vv;
        const float wgt = ok ? expf(vv - vmax) : 0.f;
        wsum += wgt; vsum += ok ? vv : 0.f;
        const float* vr = vals + (size_t)idx * D;
        accA += wgt * vr[lane];
        accB += wgt * vr[lane + 64];
        if (pkA == hh) pkA = 0ull;   // pop winner (keys unique -> pk unique)
        if (pkB == hh) pkB = 0ull;
    }
    const float inv_ws = 1.0f / wsum;
    pred[(size_t)qq * D + lane] = accA * inv_ws;
    pred[(size_t)qq * D + lane + 64] = accB * inv_ws;
    if (lane == 0) conf[qq] = fminf(fmaxf(vsum * 0.125f, 0.f), 1.f);
}

// ---------------------------------------------------------------------------
extern "C" void kernel_launch(void* const* d_in, const int* in_sizes, int n_in,
                              void* d_out, int out_size, void* d_ws, size_t ws_size,
                              hipStream_t stream) {
    const float* q    = (const float*)d_in[0];
    const float* keys = (const float*)d_in[1];
    const float* vals = (const float*)d_in[2];
    const int Q = in_sizes[0] / D;
    const int N = in_sizes[1] / D;

    int PPART = 64;  // 1024 blocks; floor 16 keeps the 8-bit tag in range
    auto need = [&](int P) {
        return (size_t)N * D * 2 + (size_t)N * 4 + (size_t)Q * D * 2 +
               2 * ((size_t)Q * P * 16 * 4) + (size_t)Q * 4 +
               (size_t)Q * CMAX * 4;
    };
    while (PPART > 16 && need(PPART) > ws_size) PPART >>= 1;

    char* ws = (char*)d_ws;
    size_t off = 0;
    u16*   kn   = (u16*)(ws + off);   off += (size_t)N * D * 2;
    float* invk = (float*)(ws + off); off += (size_t)N * 4;
    u16*   qbf  = (u16*)(ws + off);   off += (size_t)Q * D * 2;
    float* shi  = (float*)(ws + off); off += (size_t)Q * PPART * 16 * 4;
    float* ssec = (float*)(ws + off); off += (size_t)Q * PPART * 16 * 4;
    u32*   cnt  = (u32*)(ws + off);   off += (size_t)Q * 4;
    u32*   cbuf = (u32*)(ws + off);   off += (size_t)Q * CMAX * 4;

    float* pred = (float*)d_out;
    float* conf = pred + (size_t)Q * D;

    k_norm_keys<<<(N + 3) / 4, 256, 0, stream>>>(keys, q, kn, invk, qbf, cnt, N, Q);
    k_pass1<<<(Q / QB) * PPART, 256, 0, stream>>>(kn, qbf, shi, ssec, Q, N, PPART);
    k_select<<<Q / 4, 256, 0, stream>>>(shi, ssec, cnt, cbuf, Q, N, PPART);
    k_final<<<Q / 4, 256, 0, stream>>>(q, keys, vals, invk, cnt, cbuf, pred, conf, Q);
}

// Round 15
// 114.767 us; speedup vs baseline: 2.9535x; 1.0846x over previous
//
#include <hip/hip_runtime.h>
#include <stdint.h>

// SINGLE-heavy-pass pipeline (R15 = R14 pass1 FROZEN + tail fusion):
//   k_norm_keys : normalize keys -> bf16 kn + invk; cast q -> qbf
//   k_pass1     : bf16 MFMA sims, 8-bit tile tag in low mantissa bits
//                 (err <= 3e-5 << MARGIN); per-stream branchless top-2
//                 (v_med3 + v_max); the value carries the key.
//   k_finalize  : FUSED select+final. Per query-wave: T = 8th-largest
//                 stream-hi - margin; collect keys of hi/sec >= T into an
//                 LDS candidate buffer; exact fp32 re-dot -> top-8, softmax,
//                 gather vals, conf. (was k_select + cnt/cbuf + k_final)
// ws: [kn N*256B][invk N*4][qbf Q*256B][shi PPART*Q*16*4][ssec same]

typedef unsigned int u32;
typedef unsigned long long u64;
typedef unsigned short u16;
typedef __attribute__((ext_vector_type(4))) float f32x4;
typedef __attribute__((ext_vector_type(2))) float f32x2;
typedef __attribute__((ext_vector_type(4))) int i32x4;
typedef __attribute__((ext_vector_type(8))) short s16x8;  // 8 bf16 in 4 VGPRs

#define D 128
#define KTILE 64     // keys per LDS tile (16 KB, single buffer) — R7-proven
#define QW 64        // queries per wave
#define QB 256       // queries per block (4 waves)
#define CMAX 64      // candidate buffer per query
#define MARGIN 0.05f // threshold safety margin (covers bf16 + tag perturbation)
#define TBYTES (KTILE * 256)

__device__ __forceinline__ u16 f2bf(float f) {           // RNE float->bf16
    u32 b = __float_as_uint(f);
    b += 0x7FFFu + ((b >> 16) & 1u);
    return (u16)(b >> 16);
}
__device__ __forceinline__ u32 ford(float f) {            // order-preserving f32->u32
    u32 b = __float_as_uint(f);
    return (b & 0x80000000u) ? ~b : (b | 0x80000000u);
}
__device__ __forceinline__ float ford_inv(u32 ob) {
    u32 b = (ob & 0x80000000u) ? (ob ^ 0x80000000u) : ~ob;
    return __uint_as_float(b);
}

// ------- kernel 1: normalize keys -> bf16 + invk; raw-cast q -> qbf ---------
__global__ __launch_bounds__(256) void k_norm_keys(
        const float* __restrict__ keys, const float* __restrict__ q,
        u16* __restrict__ kn, float* __restrict__ invk, u16* __restrict__ qbf,
        int N, int Q) {
    int row = blockIdx.x * 4 + (threadIdx.x >> 6);
    int lane = threadIdx.x & 63;
    if (row >= N) return;
    if (row < Q) {
        f32x2 qv = *(const f32x2*)(q + (size_t)row * D + lane * 2);
        u32 qp = (u32)f2bf(qv.x) | ((u32)f2bf(qv.y) << 16);   // RAW cast (scale-free)
        *(u32*)(qbf + (size_t)row * D + lane * 2) = qp;
    }
    const float* kr = keys + (size_t)row * D;
    f32x2 v = *(const f32x2*)(kr + lane * 2);
    float ss = v.x * v.x + v.y * v.y;
    #pragma unroll
    for (int o = 1; o < 64; o <<= 1) ss += __shfl_xor(ss, o);
    float inv = 1.0f / fmaxf(sqrtf(ss), 1e-12f);
    if (lane == 0) invk[row] = inv;
    u32 packed = (u32)f2bf(v.x * inv) | ((u32)f2bf(v.y * inv) << 16);
    *(u32*)(kn + (size_t)row * D + lane * 2) = packed;
}

// A fragments straight from qbf.
__device__ __forceinline__ void load_afr_bf(const u16* qbf, int qrow_base,
                                            int lrow, int lhi, s16x8 afr[4]) {
    const u16* qrow = qbf + (size_t)(qrow_base + lrow) * D + lhi * 8;
    #pragma unroll
    for (int s = 0; s < 4; ++s) afr[s] = *(const s16x8*)(qrow + s * 32);
}

// Block id -> (p, qb): group the nqb query-blocks of one key partition on one
// XCD (consecutive bids round-robin XCDs). Bijective when PPART % 8 == 0.
__device__ __forceinline__ void decode_bid(int bid, int nqb, int PPART,
                                           int& p, int& qb) {
    if ((PPART & 7) == 0) {
        int xcd = bid & 7, seq = bid >> 3;
        qb = seq % nqb;
        p  = (seq / nqb) * 8 + xcd;
    } else {
        p = bid / nqb; qb = bid % nqb;
    }
}

// LDS swizzle contract (R7-proven): slot (row r, 16B-granule g) holds global
// granule g ^ (r&15). Writes: reg-staged ds_write_b128 at granule g^(r&15).
// Reads: slot granule (4s+lhi)^lrow at row kt*16+lrow -> global chunk 4s+lhi.

// ---------------- kernel 2: the ONLY heavy pass — tagged top-2 per stream ---
__global__ __launch_bounds__(256, 2) void k_pass1(
        const u16* __restrict__ kn, const u16* __restrict__ qbf,
        float* __restrict__ shi, float* __restrict__ ssec,
        int Q, int N, int PPART) {
    __shared__ __align__(16) char lds[TBYTES];   // 16 KB single buffer
    const int tid = threadIdx.x;
    const int wave = tid >> 6, lane = tid & 63;
    const int lrow = lane & 15, lhi = lane >> 4;
    const int nqb = Q / QB;
    int p, qb;
    decode_bid(blockIdx.x, nqb, PPART, p, qb);
    const int part = N / PPART;
    const int key0 = p * part;
    const int qbase = qb * QB + wave * QW;

    s16x8 afr[4][4];
    #pragma unroll
    for (int qs = 0; qs < 4; ++qs) load_afr_bf(qbf, qbase + qs * 16, lrow, lhi, afr[qs]);

    float hi[4][4], sec[4][4];   // per-stream top-2 tagged values
    #pragma unroll
    for (int qs = 0; qs < 4; ++qs)
        #pragma unroll
        for (int r = 0; r < 4; ++r) { hi[qs][r] = -3.0e38f; sec[qs][r] = -3.0e38f; }

    int roff[4];
    #pragma unroll
    for (int s = 0; s < 4; ++s)
        roff[s] = lrow * 256 + ((((s << 2) + lhi) ^ lrow) << 4);

    // staging: thread t -> row t>>2, granules (t&3)*4 + 0..3 (64B contiguous)
    const int srow = tid >> 2;
    const int sg0  = (tid & 3) << 2;
    const int sx   = srow & 15;
    int woff[4];
    #pragma unroll
    for (int i = 0; i < 4; ++i) woff[i] = srow * 256 + (((sg0 + i) ^ sx) << 4);
    const char* gsrc = (const char*)kn + ((size_t)(key0 + srow)) * 256 + sg0 * 16;

    const int iters = part / KTILE;
    i32x4 v[4];
    #pragma unroll
    for (int i = 0; i < 4; ++i) v[i] = *(const i32x4*)(gsrc + i * 16);
    const char* gnext = gsrc + TBYTES;

    const f32x4 kZero = {0.f, 0.f, 0.f, 0.f};   // hoisted acc seed

    for (int kb = 0; kb < iters; ++kb) {
        __syncthreads();   // (A) prev-tile readers done
        #pragma unroll
        for (int i = 0; i < 4; ++i) *(i32x4*)(lds + woff[i]) = v[i];
        __syncthreads();   // (B) writes visible
        if (kb + 1 < iters) {   // issue AFTER barrier; drained at next (A)
            #pragma unroll
            for (int i = 0; i < 4; ++i) v[i] = *(const i32x4*)(gnext + i * 16);
            gnext += TBYTES;
        }
        __builtin_amdgcn_s_setprio(1);
        #pragma unroll
        for (int kt = 0; kt < 4; ++kt) {
            const u32 tag = (u32)((kb << 2) + kt);   // tile-of-16 index, < 256
            s16x8 bfr[4];
            #pragma unroll
            for (int s = 0; s < 4; ++s)
                bfr[s] = *(const s16x8*)(lds + roff[s] + kt * 4096);
            #pragma unroll
            for (int qs = 0; qs < 4; ++qs) {
                f32x4 acc = __builtin_amdgcn_mfma_f32_16x16x32_bf16(
                                afr[qs][0], bfr[0], kZero, 0, 0, 0);
                #pragma unroll
                for (int s = 1; s < 4; ++s)
                    acc = __builtin_amdgcn_mfma_f32_16x16x32_bf16(afr[qs][s], bfr[s], acc, 0, 0, 0);
                #pragma unroll
                for (int r = 0; r < 4; ++r) {
                    // (acc & 0xFFFFFF00) | tag — backend fuses to v_and_or_b32
                    float tf = __uint_as_float(
                        (__float_as_uint(acc[r]) & 0xFFFFFF00u) | tag);
                    float h0 = hi[qs][r];
                    sec[qs][r] = __builtin_amdgcn_fmed3f(tf, sec[qs][r], h0);
                    hi[qs][r]  = fmaxf(h0, tf);
                }
            }
        }
        __builtin_amdgcn_s_setprio(0);
    }
    // layout [p][q][16]: block writes contiguous runs
    #pragma unroll
    for (int qs = 0; qs < 4; ++qs)
        #pragma unroll
        for (int r = 0; r < 4; ++r) {
            int qq = qbase + qs * 16 + (lhi << 2) + r;
            shi [((size_t)p * Q + qq) * 16 + lrow] = hi[qs][r];
            ssec[((size_t)p * Q + qq) * 16 + lrow] = sec[qs][r];
        }
}

// -------- kernel 3: FUSED threshold + collect + exact refine + output -------
__global__ __launch_bounds__(256) void k_finalize(
        const float* __restrict__ q, const float* __restrict__ keys,
        const float* __restrict__ vals, const float* __restrict__ invk,
        const float* __restrict__ shi, const float* __restrict__ ssec,
        float* __restrict__ pred, float* __restrict__ conf,
        int Q, int N, int PPART) {
    const int w = threadIdx.x >> 6;
    const int qq = blockIdx.x * 4 + w;
    const int lane = threadIdx.x & 63;
    __shared__ float qs[4][D];
    __shared__ u32 cand[4][CMAX];
    __shared__ u32 ccnt[4];
    if (lane == 0) ccnt[w] = 0u;

    // q row into LDS + exact 1/|q|
    const float* qrow = q + (size_t)qq * D;
    f32x2 qv = *(const f32x2*)(qrow + lane * 2);
    qs[w][lane * 2] = qv.x; qs[w][lane * 2 + 1] = qv.y;
    float ss = qv.x * qv.x + qv.y * qv.y;
    #pragma unroll
    for (int o = 1; o < 64; o <<= 1) ss += __shfl_xor(ss, o);
    const float invq = 1.0f / fmaxf(sqrtf(ss), 1e-12f);

    // load this query's stream top-2 (16 streams per lane for PPART=64)
    const int nv = PPART >> 2;
    float v[16], hv[16], sc[16];
    #pragma unroll
    for (int i = 0; i < 16; ++i) {
        if (i < nv) {
            size_t base = ((size_t)(i * 4 + (lane >> 4)) * Q + qq) * 16 + (lane & 15);
            hv[i] = v[i] = shi[base];
            sc[i] = ssec[base];
        } else { hv[i] = v[i] = sc[i] = -3.0e38f; }
    }
    // T = 8th-largest stream-hi (knockout; dups collapse -> smaller T = safe)
    float h = -3.0e38f;
    #pragma unroll
    for (int round = 0; round < 8; ++round) {
        h = v[0];
        #pragma unroll
        for (int i = 1; i < 16; ++i) h = fmaxf(h, v[i]);
        #pragma unroll
        for (int o = 1; o < 64; o <<= 1) h = fmaxf(h, __shfl_xor(h, o));
        #pragma unroll
        for (int i = 0; i < 16; ++i) if (v[i] == h) v[i] = -3.0e38f;
    }
    const float T = h - MARGIN;
    const int part = N / PPART;
    #pragma unroll
    for (int i = 0; i < 16; ++i) {
        if (i >= nv) break;
        const int sidx = i * 64 + lane;        // stream = (p = sidx>>4, j = sidx&15)
        const int p = sidx >> 4, j = sidx & 15;
        if (hv[i] >= T) {                      // rare (~10-20 per query)
            u32 key = (u32)(p * part + (int)((__float_as_uint(hv[i]) & 255u) << 4) + j);
            u32 pos = atomicAdd(&ccnt[w], 1u);
            if (pos < CMAX) cand[w][pos] = key;
        }
        if (sc[i] >= T) {
            u32 key = (u32)(p * part + (int)((__float_as_uint(sc[i]) & 255u) << 4) + j);
            u32 pos = atomicAdd(&ccnt[w], 1u);
            if (pos < CMAX) cand[w][pos] = key;
        }
    }
    __syncthreads();   // qs + cand + ccnt visible to all lanes

    const u32 n = min(ccnt[w], (u32)CMAX);   // >= 8 by construction
    const int c0 = lane >> 1;                // candidates c0 and c0+32
    const int half = lane & 1;
    const bool valid0 = (u32)c0 < n;
    const bool valid1 = (u32)(c0 + 32) < n;
    const u32 key0 = valid0 ? cand[w][c0] : 0u;
    const u32 key1 = valid1 ? cand[w][c0 + 32] : 0u;

    const float* qsp = &qs[w][half * 64];
    float dot0 = 0.f, dot1 = 0.f;
    {
        const float* kr0 = keys + (size_t)key0 * D + half * 64;
        const float* kr1 = keys + (size_t)key1 * D + half * 64;
        #pragma unroll
        for (int j = 0; j < 64; j += 4) {
            f32x4 a = *(const f32x4*)(kr0 + j);
            f32x4 b = *(const f32x4*)(kr1 + j);
            dot0 += a.x * qsp[j] + a.y * qsp[j + 1] + a.z * qsp[j + 2] + a.w * qsp[j + 3];
            dot1 += b.x * qsp[j] + b.y * qsp[j + 1] + b.z * qsp[j + 2] + b.w * qsp[j + 3];
        }
    }
    dot0 += __shfl_xor(dot0, 1);
    dot1 += __shfl_xor(dot1, 1);
    const float ex0 = dot0 * invk[key0] * invq;
    const float ex1 = dot1 * invk[key1] * invq;
    // pack with ~key so ties prefer the smaller index (jax top_k order)
    u64 pkA = valid0 ? (((u64)ford(ex0) << 32) | (u32)(~key0)) : 0ull;
    u64 pkB = valid1 ? (((u64)ford(ex1) << 32) | (u32)(~key1)) : 0ull;

    float accA = 0.f, accB = 0.f, wsum = 0.f, vsum = 0.f, vmax = 0.f;
    #pragma unroll
    for (int r = 0; r < 8; ++r) {
        u64 mx = pkA > pkB ? pkA : pkB;
        u64 hh = mx;
        #pragma unroll
        for (int o = 1; o < 64; o <<= 1) {
            u64 tt = __shfl_xor(hh, o);
            hh = tt > hh ? tt : hh;
        }
        const bool ok = (hh != 0ull);
        const float vv = ford_inv((u32)(hh >> 32));
        const u32 idx = ok ? ~((u32)hh) : 0u;
        if (r == 0) vmax = vv;
        const float wgt = ok ? expf(vv - vmax) : 0.f;
        wsum += wgt; vsum += ok ? vv : 0.f;
        const float* vr = vals + (size_t)idx * D;
        accA += wgt * vr[lane];
        accB += wgt * vr[lane + 64];
        if (pkA == hh) pkA = 0ull;   // pop winner (keys unique -> pk unique)
        if (pkB == hh) pkB = 0ull;
    }
    const float inv_ws = 1.0f / wsum;
    pred[(size_t)qq * D + lane] = accA * inv_ws;
    pred[(size_t)qq * D + lane + 64] = accB * inv_ws;
    if (lane == 0) conf[qq] = fminf(fmaxf(vsum * 0.125f, 0.f), 1.f);
}

// ---------------------------------------------------------------------------
extern "C" void kernel_launch(void* const* d_in, const int* in_sizes, int n_in,
                              void* d_out, int out_size, void* d_ws, size_t ws_size,
                              hipStream_t stream) {
    const float* q    = (const float*)d_in[0];
    const float* keys = (const float*)d_in[1];
    const float* vals = (const float*)d_in[2];
    const int Q = in_sizes[0] / D;
    const int N = in_sizes[1] / D;

    int PPART = 64;  // 1024 blocks; floor 16 keeps the 8-bit tag in range
    auto need = [&](int P) {
        return (size_t)N * D * 2 + (size_t)N * 4 + (size_t)Q * D * 2 +
               2 * ((size_t)Q * P * 16 * 4);
    };
    while (PPART > 16 && need(PPART) > ws_size) PPART >>= 1;

    char* ws = (char*)d_ws;
    size_t off = 0;
    u16*   kn   = (u16*)(ws + off);   off += (size_t)N * D * 2;
    float* invk = (float*)(ws + off); off += (size_t)N * 4;
    u16*   qbf  = (u16*)(ws + off);   off += (size_t)Q * D * 2;
    float* shi  = (float*)(ws + off); off += (size_t)Q * PPART * 16 * 4;
    float* ssec = (float*)(ws + off); off += (size_t)Q * PPART * 16 * 4;

    float* pred = (float*)d_out;
    float* conf = pred + (size_t)Q * D;

    k_norm_keys<<<(N + 3) / 4, 256, 0, stream>>>(keys, q, kn, invk, qbf, N, Q);
    k_pass1<<<(Q / QB) * PPART, 256, 0, stream>>>(kn, qbf, shi, ssec, Q, N, PPART);
    k_finalize<<<Q / 4, 256, 0, stream>>>(q, keys, vals, invk, shi, ssec,
                                          pred, conf, Q, N, PPART);
}

// Round 16
// 105.666 us; speedup vs baseline: 3.2079x; 1.0861x over previous
//
#include <hip/hip_runtime.h>
#include <stdint.h>

// SINGLE-heavy-pass pipeline (R16 = R15 + pair-merge top-2 update in pass1):
//   k_norm_keys : normalize keys -> bf16 kn + invk; cast q -> qbf
//   k_pass1     : bf16 MFMA sims, 8-bit tile tag in low mantissa bits
//                 (err <= 3e-5 << MARGIN); per-stream branchless top-2.
//                 R16: results merged in PAIRS (kt even/odd):
//                   hi' = max3(hi, fa, fb); sec' = max(med3(hi, fa, fb), sec)
//                 [proof: sec<=hi => 2nd-of-4 = max(2nd-of-{hi,fa,fb}, sec)]
//                 = 5 VALU per 2 results (vs 6) when max3 fuses.
//   k_finalize  : FUSED select+final (R15-proven): T = 8th stream-hi - margin;
//                 collect hi/sec >= T into LDS cand buffer; exact fp32 re-dot
//                 -> top-8, softmax, gather, conf.
// ws: [kn N*256B][invk N*4][qbf Q*256B][shi PPART*Q*16*4][ssec same]

typedef unsigned int u32;
typedef unsigned long long u64;
typedef unsigned short u16;
typedef __attribute__((ext_vector_type(4))) float f32x4;
typedef __attribute__((ext_vector_type(2))) float f32x2;
typedef __attribute__((ext_vector_type(4))) int i32x4;
typedef __attribute__((ext_vector_type(8))) short s16x8;  // 8 bf16 in 4 VGPRs

#define D 128
#define KTILE 64     // keys per LDS tile (16 KB, single buffer) — R7-proven
#define QW 64        // queries per wave
#define QB 256       // queries per block (4 waves)
#define CMAX 64      // candidate buffer per query
#define MARGIN 0.05f // threshold safety margin (covers bf16 + tag perturbation)
#define TBYTES (KTILE * 256)

__device__ __forceinline__ u16 f2bf(float f) {           // RNE float->bf16
    u32 b = __float_as_uint(f);
    b += 0x7FFFu + ((b >> 16) & 1u);
    return (u16)(b >> 16);
}
__device__ __forceinline__ u32 ford(float f) {            // order-preserving f32->u32
    u32 b = __float_as_uint(f);
    return (b & 0x80000000u) ? ~b : (b | 0x80000000u);
}
__device__ __forceinline__ float ford_inv(u32 ob) {
    u32 b = (ob & 0x80000000u) ? (ob ^ 0x80000000u) : ~ob;
    return __uint_as_float(b);
}

// ------- kernel 1: normalize keys -> bf16 + invk; raw-cast q -> qbf ---------
__global__ __launch_bounds__(256) void k_norm_keys(
        const float* __restrict__ keys, const float* __restrict__ q,
        u16* __restrict__ kn, float* __restrict__ invk, u16* __restrict__ qbf,
        int N, int Q) {
    int row = blockIdx.x * 4 + (threadIdx.x >> 6);
    int lane = threadIdx.x & 63;
    if (row >= N) return;
    if (row < Q) {
        f32x2 qv = *(const f32x2*)(q + (size_t)row * D + lane * 2);
        u32 qp = (u32)f2bf(qv.x) | ((u32)f2bf(qv.y) << 16);   // RAW cast (scale-free)
        *(u32*)(qbf + (size_t)row * D + lane * 2) = qp;
    }
    const float* kr = keys + (size_t)row * D;
    f32x2 v = *(const f32x2*)(kr + lane * 2);
    float ss = v.x * v.x + v.y * v.y;
    #pragma unroll
    for (int o = 1; o < 64; o <<= 1) ss += __shfl_xor(ss, o);
    float inv = 1.0f / fmaxf(sqrtf(ss), 1e-12f);
    if (lane == 0) invk[row] = inv;
    u32 packed = (u32)f2bf(v.x * inv) | ((u32)f2bf(v.y * inv) << 16);
    *(u32*)(kn + (size_t)row * D + lane * 2) = packed;
}

// A fragments straight from qbf.
__device__ __forceinline__ void load_afr_bf(const u16* qbf, int qrow_base,
                                            int lrow, int lhi, s16x8 afr[4]) {
    const u16* qrow = qbf + (size_t)(qrow_base + lrow) * D + lhi * 8;
    #pragma unroll
    for (int s = 0; s < 4; ++s) afr[s] = *(const s16x8*)(qrow + s * 32);
}

// Block id -> (p, qb): group the nqb query-blocks of one key partition on one
// XCD (consecutive bids round-robin XCDs). Bijective when PPART % 8 == 0.
__device__ __forceinline__ void decode_bid(int bid, int nqb, int PPART,
                                           int& p, int& qb) {
    if ((PPART & 7) == 0) {
        int xcd = bid & 7, seq = bid >> 3;
        qb = seq % nqb;
        p  = (seq / nqb) * 8 + xcd;
    } else {
        p = bid / nqb; qb = bid % nqb;
    }
}

// LDS swizzle contract (R7-proven): slot (row r, 16B-granule g) holds global
// granule g ^ (r&15). Writes: reg-staged ds_write_b128 at granule g^(r&15).
// Reads: slot granule (4s+lhi)^lrow at row kt*16+lrow -> global chunk 4s+lhi.

// ---------------- kernel 2: the ONLY heavy pass — tagged top-2 per stream ---
__global__ __launch_bounds__(256, 2) void k_pass1(
        const u16* __restrict__ kn, const u16* __restrict__ qbf,
        float* __restrict__ shi, float* __restrict__ ssec,
        int Q, int N, int PPART) {
    __shared__ __align__(16) char lds[TBYTES];   // 16 KB single buffer
    const int tid = threadIdx.x;
    const int wave = tid >> 6, lane = tid & 63;
    const int lrow = lane & 15, lhi = lane >> 4;
    const int nqb = Q / QB;
    int p, qb;
    decode_bid(blockIdx.x, nqb, PPART, p, qb);
    const int part = N / PPART;
    const int key0 = p * part;
    const int qbase = qb * QB + wave * QW;

    s16x8 afr[4][4];
    #pragma unroll
    for (int qs = 0; qs < 4; ++qs) load_afr_bf(qbf, qbase + qs * 16, lrow, lhi, afr[qs]);

    float hi[4][4], sec[4][4];   // per-stream top-2 tagged values (hi >= sec)
    #pragma unroll
    for (int qs = 0; qs < 4; ++qs)
        #pragma unroll
        for (int r = 0; r < 4; ++r) { hi[qs][r] = -3.0e38f; sec[qs][r] = -3.0e38f; }

    int roff[4];
    #pragma unroll
    for (int s = 0; s < 4; ++s)
        roff[s] = lrow * 256 + ((((s << 2) + lhi) ^ lrow) << 4);

    // staging: thread t -> row t>>2, granules (t&3)*4 + 0..3 (64B contiguous)
    const int srow = tid >> 2;
    const int sg0  = (tid & 3) << 2;
    const int sx   = srow & 15;
    int woff[4];
    #pragma unroll
    for (int i = 0; i < 4; ++i) woff[i] = srow * 256 + (((sg0 + i) ^ sx) << 4);
    const char* gsrc = (const char*)kn + ((size_t)(key0 + srow)) * 256 + sg0 * 16;

    const int iters = part / KTILE;
    i32x4 v[4];
    #pragma unroll
    for (int i = 0; i < 4; ++i) v[i] = *(const i32x4*)(gsrc + i * 16);
    const char* gnext = gsrc + TBYTES;

    const f32x4 kZero = {0.f, 0.f, 0.f, 0.f};   // hoisted acc seed

    for (int kb = 0; kb < iters; ++kb) {
        __syncthreads();   // (A) prev-tile readers done
        #pragma unroll
        for (int i = 0; i < 4; ++i) *(i32x4*)(lds + woff[i]) = v[i];
        __syncthreads();   // (B) writes visible
        if (kb + 1 < iters) {   // issue AFTER barrier; drained at next (A)
            #pragma unroll
            for (int i = 0; i < 4; ++i) v[i] = *(const i32x4*)(gnext + i * 16);
            gnext += TBYTES;
        }
        __builtin_amdgcn_s_setprio(1);
        #pragma unroll
        for (int ktp = 0; ktp < 2; ++ktp) {      // pair of 16-key tiles
            const u32 tagA = (u32)((kb << 2) + (ktp << 1));
            const u32 tagB = tagA + 1u;
            s16x8 bfrA[4], bfrB[4];
            #pragma unroll
            for (int s = 0; s < 4; ++s) {
                bfrA[s] = *(const s16x8*)(lds + roff[s] + (ktp << 1) * 4096);
                bfrB[s] = *(const s16x8*)(lds + roff[s] + ((ktp << 1) + 1) * 4096);
            }
            #pragma unroll
            for (int qs = 0; qs < 4; ++qs) {
                f32x4 accA = __builtin_amdgcn_mfma_f32_16x16x32_bf16(
                                 afr[qs][0], bfrA[0], kZero, 0, 0, 0);
                f32x4 accB = __builtin_amdgcn_mfma_f32_16x16x32_bf16(
                                 afr[qs][0], bfrB[0], kZero, 0, 0, 0);
                #pragma unroll
                for (int s = 1; s < 4; ++s) {
                    accA = __builtin_amdgcn_mfma_f32_16x16x32_bf16(afr[qs][s], bfrA[s], accA, 0, 0, 0);
                    accB = __builtin_amdgcn_mfma_f32_16x16x32_bf16(afr[qs][s], bfrB[s], accB, 0, 0, 0);
                }
                #pragma unroll
                for (int r = 0; r < 4; ++r) {
                    // tag both results (backend fuses to v_and_or_b32)
                    float fa = __uint_as_float(
                        (__float_as_uint(accA[r]) & 0xFFFFFF00u) | tagA);
                    float fb = __uint_as_float(
                        (__float_as_uint(accB[r]) & 0xFFFFFF00u) | tagB);
                    float h0 = hi[qs][r];
                    // top-2 merge of {h0, sec} U {fa, fb}  (sec <= h0)
                    sec[qs][r] = fmaxf(__builtin_amdgcn_fmed3f(h0, fa, fb), sec[qs][r]);
                    hi[qs][r]  = fmaxf(fmaxf(h0, fa), fb);   // -> v_max3_f32
                }
            }
        }
        __builtin_amdgcn_s_setprio(0);
    }
    // layout [p][q][16]: block writes contiguous runs
    #pragma unroll
    for (int qs = 0; qs < 4; ++qs)
        #pragma unroll
        for (int r = 0; r < 4; ++r) {
            int qq = qbase + qs * 16 + (lhi << 2) + r;
            shi [((size_t)p * Q + qq) * 16 + lrow] = hi[qs][r];
            ssec[((size_t)p * Q + qq) * 16 + lrow] = sec[qs][r];
        }
}

// -------- kernel 3: FUSED threshold + collect + exact refine + output -------
__global__ __launch_bounds__(256) void k_finalize(
        const float* __restrict__ q, const float* __restrict__ keys,
        const float* __restrict__ vals, const float* __restrict__ invk,
        const float* __restrict__ shi, const float* __restrict__ ssec,
        float* __restrict__ pred, float* __restrict__ conf,
        int Q, int N, int PPART) {
    const int w = threadIdx.x >> 6;
    const int qq = blockIdx.x * 4 + w;
    const int lane = threadIdx.x & 63;
    __shared__ float qs[4][D];
    __shared__ u32 cand[4][CMAX];
    __shared__ u32 ccnt[4];
    if (lane == 0) ccnt[w] = 0u;

    // q row into LDS + exact 1/|q|
    const float* qrow = q + (size_t)qq * D;
    f32x2 qv = *(const f32x2*)(qrow + lane * 2);
    qs[w][lane * 2] = qv.x; qs[w][lane * 2 + 1] = qv.y;
    float ss = qv.x * qv.x + qv.y * qv.y;
    #pragma unroll
    for (int o = 1; o < 64; o <<= 1) ss += __shfl_xor(ss, o);
    const float invq = 1.0f / fmaxf(sqrtf(ss), 1e-12f);

    // load this query's stream top-2 (16 streams per lane for PPART=64)
    const int nv = PPART >> 2;
    float v[16], hv[16], sc[16];
    #pragma unroll
    for (int i = 0; i < 16; ++i) {
        if (i < nv) {
            size_t base = ((size_t)(i * 4 + (lane >> 4)) * Q + qq) * 16 + (lane & 15);
            hv[i] = v[i] = shi[base];
            sc[i] = ssec[base];
        } else { hv[i] = v[i] = sc[i] = -3.0e38f; }
    }
    // T = 8th-largest stream-hi (knockout; dups collapse -> smaller T = safe)
    float h = -3.0e38f;
    #pragma unroll
    for (int round = 0; round < 8; ++round) {
        h = v[0];
        #pragma unroll
        for (int i = 1; i < 16; ++i) h = fmaxf(h, v[i]);
        #pragma unroll
        for (int o = 1; o < 64; o <<= 1) h = fmaxf(h, __shfl_xor(h, o));
        #pragma unroll
        for (int i = 0; i < 16; ++i) if (v[i] == h) v[i] = -3.0e38f;
    }
    const float T = h - MARGIN;
    const int part = N / PPART;
    #pragma unroll
    for (int i = 0; i < 16; ++i) {
        if (i >= nv) break;
        const int sidx = i * 64 + lane;        // stream = (p = sidx>>4, j = sidx&15)
        const int p = sidx >> 4, j = sidx & 15;
        if (hv[i] >= T) {                      // rare (~10-20 per query)
            u32 key = (u32)(p * part + (int)((__float_as_uint(hv[i]) & 255u) << 4) + j);
            u32 pos = atomicAdd(&ccnt[w], 1u);
            if (pos < CMAX) cand[w][pos] = key;
        }
        if (sc[i] >= T) {
            u32 key = (u32)(p * part + (int)((__float_as_uint(sc[i]) & 255u) << 4) + j);
            u32 pos = atomicAdd(&ccnt[w], 1u);
            if (pos < CMAX) cand[w][pos] = key;
        }
    }
    __syncthreads();   // qs + cand + ccnt visible to all lanes

    const u32 n = min(ccnt[w], (u32)CMAX);   // >= 8 by construction
    const int c0 = lane >> 1;                // candidates c0 and c0+32
    const int half = lane & 1;
    const bool valid0 = (u32)c0 < n;
    const bool valid1 = (u32)(c0 + 32) < n;
    const u32 key0 = valid0 ? cand[w][c0] : 0u;
    const u32 key1 = valid1 ? cand[w][c0 + 32] : 0u;

    const float* qsp = &qs[w][half * 64];
    float dot0 = 0.f, dot1 = 0.f;
    {
        const float* kr0 = keys + (size_t)key0 * D + half * 64;
        const float* kr1 = keys + (size_t)key1 * D + half * 64;
        #pragma unroll
        for (int j = 0; j < 64; j += 4) {
            f32x4 a = *(const f32x4*)(kr0 + j);
            f32x4 b = *(const f32x4*)(kr1 + j);
            dot0 += a.x * qsp[j] + a.y * qsp[j + 1] + a.z * qsp[j + 2] + a.w * qsp[j + 3];
            dot1 += b.x * qsp[j] + b.y * qsp[j + 1] + b.z * qsp[j + 2] + b.w * qsp[j + 3];
        }
    }
    dot0 += __shfl_xor(dot0, 1);
    dot1 += __shfl_xor(dot1, 1);
    const float ex0 = dot0 * invk[key0] * invq;
    const float ex1 = dot1 * invk[key1] * invq;
    // pack with ~key so ties prefer the smaller index (jax top_k order)
    u64 pkA = valid0 ? (((u64)ford(ex0) << 32) | (u32)(~key0)) : 0ull;
    u64 pkB = valid1 ? (((u64)ford(ex1) << 32) | (u32)(~key1)) : 0ull;

    float accA = 0.f, accB = 0.f, wsum = 0.f, vsum = 0.f, vmax = 0.f;
    #pragma unroll
    for (int r = 0; r < 8; ++r) {
        u64 mx = pkA > pkB ? pkA : pkB;
        u64 hh = mx;
        #pragma unroll
        for (int o = 1; o < 64; o <<= 1) {
            u64 tt = __shfl_xor(hh, o);
            hh = tt > hh ? tt : hh;
        }
        const bool ok = (hh != 0ull);
        const float vv = ford_inv((u32)(hh >> 32));
        const u32 idx = ok ? ~((u32)hh) : 0u;
        if (r == 0) vmax = vv;
        const float wgt = ok ? expf(vv - vmax) : 0.f;
        wsum += wgt; vsum += ok ? vv : 0.f;
        const float* vr = vals + (size_t)idx * D;
        accA += wgt * vr[lane];
        accB += wgt * vr[lane + 64];
        if (pkA == hh) pkA = 0ull;   // pop winner (keys unique -> pk unique)
        if (pkB == hh) pkB = 0ull;
    }
    const float inv_ws = 1.0f / wsum;
    pred[(size_t)qq * D + lane] = accA * inv_ws;
    pred[(size_t)qq * D + lane + 64] = accB * inv_ws;
    if (lane == 0) conf[qq] = fminf(fmaxf(vsum * 0.125f, 0.f), 1.f);
}

// ---------------------------------------------------------------------------
extern "C" void kernel_launch(void* const* d_in, const int* in_sizes, int n_in,
                              void* d_out, int out_size, void* d_ws, size_t ws_size,
                              hipStream_t stream) {
    const float* q    = (const float*)d_in[0];
    const float* keys = (const float*)d_in[1];
    const float* vals = (const float*)d_in[2];
    const int Q = in_sizes[0] / D;
    const int N = in_sizes[1] / D;

    int PPART = 64;  // 1024 blocks; floor 16 keeps the 8-bit tag in range
    auto need = [&](int P) {
        return (size_t)N * D * 2 + (size_t)N * 4 + (size_t)Q * D * 2 +
               2 * ((size_t)Q * P * 16 * 4);
    };
    while (PPART > 16 && need(PPART) > ws_size) PPART >>= 1;

    char* ws = (char*)d_ws;
    size_t off = 0;
    u16*   kn   = (u16*)(ws + off);   off += (size_t)N * D * 2;
    float* invk = (float*)(ws + off); off += (size_t)N * 4;
    u16*   qbf  = (u16*)(ws + off);   off += (size_t)Q * D * 2;
    float* shi  = (float*)(ws + off); off += (size_t)Q * PPART * 16 * 4;
    float* ssec = (float*)(ws + off); off += (size_t)Q * PPART * 16 * 4;

    float* pred = (float*)d_out;
    float* conf = pred + (size_t)Q * D;

    k_norm_keys<<<(N + 3) / 4, 256, 0, stream>>>(keys, q, kn, invk, qbf, N, Q);
    k_pass1<<<(Q / QB) * PPART, 256, 0, stream>>>(kn, qbf, shi, ssec, Q, N, PPART);
    k_finalize<<<Q / 4, 256, 0, stream>>>(q, keys, vals, invk, shi, ssec,
                                          pred, conf, Q, N, PPART);
}